// Round 3
// baseline (440.341 us; speedup 1.0000x reference)
//
#include <hip/hip_runtime.h>
#include <math.h>

constexpr int B  = 2048;
constexpr int S  = 200;
constexpr int D  = 64;
constexpr int H  = 4;
constexpr int H1 = 64;
constexpr int H2 = 32;
constexpr int F  = 256;

constexpr int PK    = 72;    // LDS bf16 row pitch (144B -> bank-rotating, conflict-free frags)
constexpr int SROWS = 208;   // 13 MFMA s-tiles

typedef short bf16x8 __attribute__((ext_vector_type(8)));
typedef float f32x4  __attribute__((ext_vector_type(4)));

__device__ __forceinline__ ushort f2bf(float x) {
    union { float f; unsigned u; } v; v.f = x;
    unsigned r = v.u + 0x7fffu + ((v.u >> 16) & 1u);   // RNE
    return (ushort)(r >> 16);
}
__device__ __forceinline__ float bf2f(ushort h) {
    union { unsigned u; float f; } v; v.u = ((unsigned)h) << 16; return v.f;
}

// One block per batch row. 512 threads = 8 waves, ~63 KB LDS -> 2 blocks/CU.
// Layer1 folded:  Weff[d][k] = W1[h,d,k] + W1[h,192+d,k] + q_d * W1[h,128+d,k]
//                 qt[k]      = b1[h,k] + sum_d q_d*(W1[h,64+d,k] - W1[h,192+d,k])
// Layer1 computed TRANSPOSED: D[k][s] = mfma(A=WeffT[k][d], B=keysT[d][s]).
// Layer2 B-fragments (h1T) built from registers via lane shuffles (no LDS trip).
__global__ __launch_bounds__(512, 4) void fused_kernel(
    const float* __restrict__ query, const float* __restrict__ keys,
    const int* __restrict__ mask,
    const float* __restrict__ W1, const float* __restrict__ b1, const float* __restrict__ a1,
    const float* __restrict__ W2, const float* __restrict__ b2, const float* __restrict__ a2,
    const float* __restrict__ W3, const float* __restrict__ b3,
    const float* __restrict__ Wo, const float* __restrict__ bo,
    float* __restrict__ out)
{
    __shared__ ushort sKh[SROWS * PK];          // keys bf16 [s][d]
    __shared__ union UU {
        struct { ushort WTh[H1 * PK], WTl[H1 * PK],     // WeffT [k][d] hi/lo
                        W2Th[H2 * PK], W2Tl[H2 * PK]; } w;  // W2T [m][k] hi/lo
        struct { float4 sw4[SROWS]; float sred[8][4][64]; float po[8][64]; float comb[64]; } a;
    } U;
    __shared__ float sQ[64];
    __shared__ float sQt[H][64];
    __shared__ float sB2[H][32], sW3v[H][32];
    __shared__ float sScores[H][SROWS];

    const int b    = blockIdx.x;
    const int t    = threadIdx.x;
    const int lane = t & 63;
    const int wave = t >> 6;
    const int g    = lane >> 4;     // 4 lane-groups
    const int ln16 = lane & 15;

    // ---------------- stage keys (bf16), query, small consts ----------------
    {
        const float4* k4 = (const float4*)(keys + (size_t)b * S * D);
        for (int idx = t; idx < S * D / 4; idx += 512) {
            float4 v = k4[idx];
            int s = idx >> 4, dc = (idx & 15) * 4;
            ushort4 hv; hv.x = f2bf(v.x); hv.y = f2bf(v.y); hv.z = f2bf(v.z); hv.w = f2bf(v.w);
            *(ushort4*)&sKh[s * PK + dc] = hv;
        }
        for (int idx = t; idx < 8 * PK; idx += 512) sKh[200 * PK + idx] = 0;  // zero pad rows
        if (t < 64) sQ[t] = query[(size_t)b * D + t];
        if (t < 128) { int hh = t >> 5, m = t & 31; sB2[hh][m] = b2[hh * 32 + m]; sW3v[hh][m] = W3[hh * 32 + m]; }
    }
    __syncthreads();

    const int src0 = ln16 + ((g & 1) ? 32 : 0);   // shuffle sources for layer2 B-frag
    const int src1 = src0 + 16;
    const int sel  = g >> 1;

    // ---------------- per-head MLP ----------------
    for (int h = 0; h < H; ++h) {
        // build WeffT [k][d] hi/lo and W2T [m][k] hi/lo
        {
            const float* w1h = W1 + (size_t)h * F * H1;
            const int k = t & 63, dg = t >> 6;
            #pragma unroll
            for (int j = 0; j < 8; ++j) {
                int d = dg * 8 + j;
                float w = w1h[d * 64 + k] + w1h[(192 + d) * 64 + k] + sQ[d] * w1h[(128 + d) * 64 + k];
                ushort hi = f2bf(w);
                U.w.WTh[k * PK + d] = hi;
                U.w.WTl[k * PK + d] = f2bf(w - bf2f(hi));
            }
            const float* w2h = W2 + (size_t)h * H1 * H2;
            const int m = t & 31, kg = t >> 5;   // kg = 0..15
            #pragma unroll
            for (int j = 0; j < 4; ++j) {
                int k2 = kg * 4 + j;
                float w = w2h[k2 * 32 + m];
                ushort hi = f2bf(w);
                U.w.W2Th[m * PK + k2] = hi;
                U.w.W2Tl[m * PK + k2] = f2bf(w - bf2f(hi));
            }
        }
        if (h == 0 && t < 256) {   // qt for all heads, overlapped with head-0 weight build
            int hh = t >> 6, k = t & 63;
            const float* w1h = W1 + (size_t)hh * F * H1;
            float acc = b1[hh * 64 + k];
            #pragma unroll 8
            for (int d = 0; d < 64; ++d)
                acc += sQ[d] * (w1h[(64 + d) * 64 + k] - w1h[(192 + d) * 64 + k]);
            sQt[hh][k] = acc;
        }
        __syncthreads();

        const float a1v = a1[h], a2v = a2[h], b3v = b3[h];

        for (int st = wave; st < 13; st += 8) {
            // ---- layer 1 (transposed): acc[mt] = D[k-tile mt][s-tile st] ----
            f32x4 acc[4] = { {0,0,0,0},{0,0,0,0},{0,0,0,0},{0,0,0,0} };
            #pragma unroll
            for (int kk = 0; kk < 2; ++kk) {
                const int koff = kk * 32 + g * 8;
                bf16x8 bk = *(const bf16x8*)&sKh[(st * 16 + ln16) * PK + koff];
                #pragma unroll
                for (int mt = 0; mt < 4; ++mt) {
                    bf16x8 wh = *(const bf16x8*)&U.w.WTh[(mt * 16 + ln16) * PK + koff];
                    bf16x8 wl = *(const bf16x8*)&U.w.WTl[(mt * 16 + ln16) * PK + koff];
                    acc[mt] = __builtin_amdgcn_mfma_f32_16x16x32_bf16(wl, bk, acc[mt], 0, 0, 0);
                    acc[mt] = __builtin_amdgcn_mfma_f32_16x16x32_bf16(wh, bk, acc[mt], 0, 0, 0);
                }
            }

            // ---- epilogue: +qt, prelu, split hi/lo, pack to bf16x2 words ----
            // lane holds h1T[k][s]: s = ln16, k = 16*mt + 4*g + i
            unsigned ph[4][2], pl[4][2];
            #pragma unroll
            for (int mt = 0; mt < 4; ++mt) {
                ushort hw[4], lw[4];
                #pragma unroll
                for (int i = 0; i < 4; ++i) {
                    float v = acc[mt][i] + sQt[h][mt * 16 + g * 4 + i];
                    v = v > 0.f ? v : a1v * v;
                    ushort hi = f2bf(v);
                    hw[i] = hi;
                    lw[i] = f2bf(v - bf2f(hi));
                }
                ph[mt][0] = (unsigned)hw[0] | ((unsigned)hw[1] << 16);
                ph[mt][1] = (unsigned)hw[2] | ((unsigned)hw[3] << 16);
                pl[mt][0] = (unsigned)lw[0] | ((unsigned)lw[1] << 16);
                pl[mt][1] = (unsigned)lw[2] | ((unsigned)lw[3] << 16);
            }

            // ---- layer 2: D2[m][s] = W2T x h1T, B-frags via shuffles ----
            f32x4 acc2[2] = { {0,0,0,0},{0,0,0,0} };
            #pragma unroll
            for (int w = 0; w < 2; ++w) {
                union { unsigned u[4]; bf16x8 v; } Bh, Bl;
                {
                    int t0, t1;
                    t0 = __shfl((int)ph[2*w][0], src0); t1 = __shfl((int)ph[2*w+1][0], src0);
                    Bh.u[0] = (unsigned)(sel ? t1 : t0);
                    t0 = __shfl((int)ph[2*w][1], src0); t1 = __shfl((int)ph[2*w+1][1], src0);
                    Bh.u[1] = (unsigned)(sel ? t1 : t0);
                    t0 = __shfl((int)ph[2*w][0], src1); t1 = __shfl((int)ph[2*w+1][0], src1);
                    Bh.u[2] = (unsigned)(sel ? t1 : t0);
                    t0 = __shfl((int)ph[2*w][1], src1); t1 = __shfl((int)ph[2*w+1][1], src1);
                    Bh.u[3] = (unsigned)(sel ? t1 : t0);
                    t0 = __shfl((int)pl[2*w][0], src0); t1 = __shfl((int)pl[2*w+1][0], src0);
                    Bl.u[0] = (unsigned)(sel ? t1 : t0);
                    t0 = __shfl((int)pl[2*w][1], src0); t1 = __shfl((int)pl[2*w+1][1], src0);
                    Bl.u[1] = (unsigned)(sel ? t1 : t0);
                    t0 = __shfl((int)pl[2*w][0], src1); t1 = __shfl((int)pl[2*w+1][0], src1);
                    Bl.u[2] = (unsigned)(sel ? t1 : t0);
                    t0 = __shfl((int)pl[2*w][1], src1); t1 = __shfl((int)pl[2*w+1][1], src1);
                    Bl.u[3] = (unsigned)(sel ? t1 : t0);
                }
                #pragma unroll
                for (int mt2 = 0; mt2 < 2; ++mt2) {
                    const int aoff = (mt2 * 16 + ln16) * PK + w * 32 + g * 8;
                    bf16x8 a2h = *(const bf16x8*)&U.w.W2Th[aoff];
                    bf16x8 a2l = *(const bf16x8*)&U.w.W2Tl[aoff];
                    acc2[mt2] = __builtin_amdgcn_mfma_f32_16x16x32_bf16(a2l, Bh.v, acc2[mt2], 0, 0, 0);
                    acc2[mt2] = __builtin_amdgcn_mfma_f32_16x16x32_bf16(a2h, Bl.v, acc2[mt2], 0, 0, 0);
                    acc2[mt2] = __builtin_amdgcn_mfma_f32_16x16x32_bf16(a2h, Bh.v, acc2[mt2], 0, 0, 0);
                }
            }

            // ---- layer 3: prelu + dot(W3), reduce over lane-groups ----
            float part = 0.f;
            #pragma unroll
            for (int mt2 = 0; mt2 < 2; ++mt2) {
                #pragma unroll
                for (int i = 0; i < 4; ++i) {
                    const int m = mt2 * 16 + g * 4 + i;
                    float v = acc2[mt2][i] + sB2[h][m];
                    v = v > 0.f ? v : a2v * v;
                    part += v * sW3v[h][m];
                }
            }
            part += __shfl_xor(part, 16);
            part += __shfl_xor(part, 32);
            if (lane < 16) {
                int s = st * 16 + lane;
                if (s < 200) sScores[h][s] = part + b3v;
            }
        }
        __syncthreads();   // weights buffer free for next head / attend union
    }

    // ---------------- attend: masked softmax (wave per head) ----------------
    if (wave < 4) {
        const int hh = wave;
        float v[4]; int valid[4];
        float M = -INFINITY;
        #pragma unroll
        for (int c = 0; c < 4; ++c) {
            int s = lane + 64 * c;
            bool ok = s < S;
            valid[c] = ok ? mask[(size_t)b * S + s] : 0;
            v[c] = (ok && valid[c]) ? sScores[hh][s] : -INFINITY;
            M = fmaxf(M, v[c]);
        }
        #pragma unroll
        for (int off = 32; off > 0; off >>= 1) M = fmaxf(M, __shfl_xor(M, off));
        float Z = 0.f, e[4];
        #pragma unroll
        for (int c = 0; c < 4; ++c) { e[c] = valid[c] ? __expf(v[c] - M) : 0.f; Z += e[c]; }
        #pragma unroll
        for (int off = 32; off > 0; off >>= 1) Z += __shfl_xor(Z, off);
        float inv = Z > 0.f ? 1.f / Z : 0.f;
        #pragma unroll
        for (int c = 0; c < 4; ++c) { int s = lane + 64 * c; if (s < S) ((float*)&U.a.sw4[s])[hh] = e[c] * inv; }
    }
    __syncthreads();

    // ---------------- weighted key sum ----------------
    {
        const int d = t & 63, sg = t >> 6;
        float a0 = 0.f, s1 = 0.f, s2 = 0.f, s3 = 0.f;
        #pragma unroll 5
        for (int i = 0; i < 25; ++i) {
            int s = sg * 25 + i;
            float kv = bf2f(sKh[s * PK + d]);
            float4 wv = U.a.sw4[s];
            a0 += wv.x * kv; s1 += wv.y * kv; s2 += wv.z * kv; s3 += wv.w * kv;
        }
        U.a.sred[sg][0][d] = a0; U.a.sred[sg][1][d] = s1;
        U.a.sred[sg][2][d] = s2; U.a.sred[sg][3][d] = s3;
    }
    __syncthreads();
    if (t < 64) {
        float c = 0.f;
        #pragma unroll
        for (int i = 0; i < 32; ++i) c += U.a.sred[i >> 2][i & 3][t];
        U.a.comb[t] = c * 0.25f;
    }
    __syncthreads();

    // ---------------- output projection ----------------
    {
        const int col = t & 63, gq = t >> 6;
        float p = 0.f;
        #pragma unroll
        for (int j = 0; j < 8; ++j) { int dd = gq * 8 + j; p += U.a.comb[dd] * Wo[dd * 64 + col]; }
        U.a.po[gq][col] = p;
    }
    __syncthreads();
    if (t < 64) {
        float o = bo[t];
        #pragma unroll
        for (int gq = 0; gq < 8; ++gq) o += U.a.po[gq][t];
        out[(size_t)b * D + t] = o;
    }
}

extern "C" void kernel_launch(void* const* d_in, const int* in_sizes, int n_in,
                              void* d_out, int out_size, void* d_ws, size_t ws_size,
                              hipStream_t stream) {
    const float* query = (const float*)d_in[0];
    const float* keys  = (const float*)d_in[1];
    const int*   mask  = (const int*)d_in[2];
    const float* W1 = (const float*)d_in[3];
    const float* b1 = (const float*)d_in[4];
    const float* a1 = (const float*)d_in[5];
    const float* W2 = (const float*)d_in[6];
    const float* b2 = (const float*)d_in[7];
    const float* a2 = (const float*)d_in[8];
    const float* W3 = (const float*)d_in[9];
    const float* b3 = (const float*)d_in[10];
    const float* Wo = (const float*)d_in[11];
    const float* bo = (const float*)d_in[12];

    fused_kernel<<<dim3(B), 512, 0, stream>>>(query, keys, mask,
                                              W1, b1, a1, W2, b2, a2, W3, b3,
                                              Wo, bo, (float*)d_out);
}

// Round 4
// 123.421 us; speedup vs baseline: 3.5678x; 3.5678x over previous
//
#include <hip/hip_runtime.h>
#include <math.h>

constexpr int B  = 2048;
constexpr int S  = 200;
constexpr int D  = 64;
constexpr int H  = 4;
constexpr int H1 = 64;
constexpr int H2 = 32;
constexpr int F  = 256;

constexpr int PW = 72;   // bf16 LDS pitch: 144 B rows -> >=16B aligned, ~2-way banks (free)

typedef short bf16x8 __attribute__((ext_vector_type(8)));
typedef float f32x4  __attribute__((ext_vector_type(4)));
typedef unsigned uint4v __attribute__((ext_vector_type(4)));

__device__ __forceinline__ ushort f2bf(float x) {
    union { float f; unsigned u; } v; v.f = x;
    unsigned r = v.u + 0x7fffu + ((v.u >> 16) & 1u);   // RNE
    return (ushort)(r >> 16);
}
__device__ __forceinline__ float bf2f(ushort h) {
    union { unsigned u; float f; } v; v.u = ((unsigned)h) << 16; return v.f;
}
// packed f32->bf16 (RNE on gfx950): low16 = cvt(a), high16 = cvt(b)
__device__ __forceinline__ unsigned cvtpk(float a, float b) {
    unsigned r;
    asm volatile("v_cvt_pk_bf16_f32 %0, %1, %2" : "=v"(r) : "v"(a), "v"(b));
    return r;
}
__device__ __forceinline__ float lo16f(unsigned w) { return __builtin_bit_cast(float, w << 16); }
__device__ __forceinline__ float hi16f(unsigned w) { return __builtin_bit_cast(float, w & 0xffff0000u); }

// ---------------------------------------------------------------------------
// Score kernel: one block per (b,h), 256 threads = 4 waves.
//   Weff[d][k] = W1[h,d,k] + W1[h,192+d,k] + q_d * W1[h,128+d,k]
//   qt[k]      = b1[h,k] + sum_d q_d*(W1[h,64+d,k] - W1[h,192+d,k])
//   h1T = WeffT @ keysT (transposed layer1), layer2 via wave-private LDS relay.
// ---------------------------------------------------------------------------
__global__ __launch_bounds__(256, 2) void score_kernel(
    const float* __restrict__ query, const float* __restrict__ keys,
    const float* __restrict__ W1, const float* __restrict__ b1, const float* __restrict__ a1,
    const float* __restrict__ W2, const float* __restrict__ b2, const float* __restrict__ a2,
    const float* __restrict__ W3, const float* __restrict__ b3,
    float* __restrict__ scores)
{
    __shared__ ushort sWTh[H1 * PW], sWTl[H1 * PW];   // WeffT [k][d] hi/lo
    __shared__ ushort sW2h[H2 * PW], sW2l[H2 * PW];   // W2T  [m][k] hi/lo
    __shared__ ushort sH1h[4][16 * PW], sH1l[4][16 * PW];  // per-wave h1 relay [s16][k]
    __shared__ float sQ[64], sQt[64], sQp[4][64];
    __shared__ float sB2[32], sW3v[32];

    // XCD-bijective swizzle: the 4 h-blocks of each b land on the same XCD, adjacent in time.
    const int wg   = blockIdx.x;
    const int rank = (wg & 7) * 1024 + (wg >> 3);
    const int b = rank >> 2;
    const int h = rank & 3;

    const int t    = threadIdx.x;
    const int lane = t & 63;
    const int wave = t >> 6;
    const int g    = lane >> 4;
    const int ln16 = lane & 15;

    const float* w1h = W1 + (size_t)h * F * H1;

    // ---- P0: stage q, build W2T hi/lo, stage b2/W3 ----
    if (t < 64) sQ[t] = query[(size_t)b * D + t];
    else if (t < 192) {
        const float* w2h = W2 + (size_t)h * H1 * H2;
        int idx = t - 64, m = idx & 31, kg = idx >> 5;
        #pragma unroll
        for (int j = 0; j < 4; ++j) {
            int k2 = kg * 4 + j * 4 + (idx & 0);   // k2 = kg*16.. keep simple below
            (void)k2;
        }
        #pragma unroll
        for (int j = 0; j < 16; ++j) {
            int k2 = kg * 16 + j;
            float w = w2h[k2 * 32 + m];
            ushort hi = f2bf(w);
            sW2h[m * PW + k2] = hi;
            sW2l[m * PW + k2] = f2bf(w - bf2f(hi));
        }
    } else {
        int t3 = t - 192;
        if (t3 < 32) sB2[t3] = b2[h * 32 + t3];
        else if (t3 < 64) sW3v[t3 - 32] = W3[h * 32 + (t3 - 32)];
    }
    __syncthreads();

    // ---- P1: build WeffT hi/lo + qt partials ----
    {
        const int k = t & 63, dg = t >> 6;
        float qtp = 0.f;
        #pragma unroll
        for (int j = 0; j < 16; ++j) {
            int d = dg * 16 + j;
            float wA = w1h[d * 64 + k];
            float wB = w1h[(64 + d) * 64 + k];
            float wC = w1h[(128 + d) * 64 + k];
            float wD = w1h[(192 + d) * 64 + k];
            float w = wA + wD + sQ[d] * wC;
            ushort hi = f2bf(w);
            sWTh[k * PW + d] = hi;
            sWTl[k * PW + d] = f2bf(w - bf2f(hi));
            qtp += sQ[d] * (wB - wD);
        }
        sQp[dg][k] = qtp;
    }
    __syncthreads();

    if (t < 64) sQt[t] = b1[h * 64 + t] + sQp[0][t] + sQp[1][t] + sQp[2][t] + sQp[3][t];
    __syncthreads();

    // ---- hoist invariant fragments into registers ----
    bf16x8 wh[4][2], wl[4][2];
    #pragma unroll
    for (int mt = 0; mt < 4; ++mt)
        #pragma unroll
        for (int kk = 0; kk < 2; ++kk) {
            int off = (mt * 16 + ln16) * PW + kk * 32 + g * 8;
            wh[mt][kk] = *(const bf16x8*)&sWTh[off];
            wl[mt][kk] = *(const bf16x8*)&sWTl[off];
        }
    f32x4 qtv[4];
    #pragma unroll
    for (int mt = 0; mt < 4; ++mt) qtv[mt] = *(const f32x4*)&sQt[mt * 16 + g * 4];
    f32x4 b2v[2], w3v[2];
    #pragma unroll
    for (int mt2 = 0; mt2 < 2; ++mt2) {
        b2v[mt2] = *(const f32x4*)&sB2[mt2 * 16 + g * 4];
        w3v[mt2] = *(const f32x4*)&sW3v[mt2 * 16 + g * 4];
    }
    const float a1v = a1[h], a2v = a2[h], b3v = b3[h];
    ushort* myH1h = sH1h[wave];
    ushort* myH1l = sH1l[wave];

    // ---- main loop: barrier-free, 13 s-tiles over 4 waves ----
    for (int st = wave; st < 13; st += 4) {
        const int s = st * 16 + ln16;
        const int s_ld = s < 200 ? s : 199;
        const float* krow = keys + ((size_t)b * S + s_ld) * D;

        float4 kA0 = *(const float4*)&krow[g * 8];
        float4 kA1 = *(const float4*)&krow[g * 8 + 4];
        float4 kB0 = *(const float4*)&krow[32 + g * 8];
        float4 kB1 = *(const float4*)&krow[32 + g * 8 + 4];
        uint4v u0 = { cvtpk(kA0.x, kA0.y), cvtpk(kA0.z, kA0.w),
                      cvtpk(kA1.x, kA1.y), cvtpk(kA1.z, kA1.w) };
        uint4v u1 = { cvtpk(kB0.x, kB0.y), cvtpk(kB0.z, kB0.w),
                      cvtpk(kB1.x, kB1.y), cvtpk(kB1.z, kB1.w) };
        bf16x8 bk0 = __builtin_bit_cast(bf16x8, u0);
        bf16x8 bk1 = __builtin_bit_cast(bf16x8, u1);

        // layer 1 (transposed): acc[mt] holds h1T[k=16mt+4g+i][s-col=ln16]
        f32x4 acc[4] = { {0,0,0,0},{0,0,0,0},{0,0,0,0},{0,0,0,0} };
        #pragma unroll
        for (int mt = 0; mt < 4; ++mt) {
            acc[mt] = __builtin_amdgcn_mfma_f32_16x16x32_bf16(wl[mt][0], bk0, acc[mt], 0, 0, 0);
            acc[mt] = __builtin_amdgcn_mfma_f32_16x16x32_bf16(wh[mt][0], bk0, acc[mt], 0, 0, 0);
        }
        #pragma unroll
        for (int mt = 0; mt < 4; ++mt) {
            acc[mt] = __builtin_amdgcn_mfma_f32_16x16x32_bf16(wl[mt][1], bk1, acc[mt], 0, 0, 0);
            acc[mt] = __builtin_amdgcn_mfma_f32_16x16x32_bf16(wh[mt][1], bk1, acc[mt], 0, 0, 0);
        }

        // epilogue: +qt, prelu, hi/lo split, relay via wave-private LDS (B-frag layout)
        #pragma unroll
        for (int mt = 0; mt < 4; ++mt) {
            float v0 = acc[mt][0] + qtv[mt][0]; v0 = v0 > 0.f ? v0 : a1v * v0;
            float v1 = acc[mt][1] + qtv[mt][1]; v1 = v1 > 0.f ? v1 : a1v * v1;
            float v2 = acc[mt][2] + qtv[mt][2]; v2 = v2 > 0.f ? v2 : a1v * v2;
            float v3 = acc[mt][3] + qtv[mt][3]; v3 = v3 > 0.f ? v3 : a1v * v3;
            unsigned hw0 = cvtpk(v0, v1), hw1 = cvtpk(v2, v3);
            unsigned lw0 = cvtpk(v0 - lo16f(hw0), v1 - hi16f(hw0));
            unsigned lw1 = cvtpk(v2 - lo16f(hw1), v3 - hi16f(hw1));
            const int koff = ln16 * PW + mt * 16 + g * 4;
            *(uint2*)&myH1h[koff] = make_uint2(hw0, hw1);
            *(uint2*)&myH1l[koff] = make_uint2(lw0, lw1);
        }

        // layer 2: D2[m][s] = W2T @ h1T
        f32x4 acc2[2] = { {0,0,0,0},{0,0,0,0} };
        #pragma unroll
        for (int w = 0; w < 2; ++w) {
            bf16x8 Bh = *(const bf16x8*)&myH1h[ln16 * PW + w * 32 + g * 8];
            bf16x8 Bl = *(const bf16x8*)&myH1l[ln16 * PW + w * 32 + g * 8];
            #pragma unroll
            for (int mt2 = 0; mt2 < 2; ++mt2) {
                int off = (mt2 * 16 + ln16) * PW + w * 32 + g * 8;
                bf16x8 ah = *(const bf16x8*)&sW2h[off];
                bf16x8 al = *(const bf16x8*)&sW2l[off];
                acc2[mt2] = __builtin_amdgcn_mfma_f32_16x16x32_bf16(al, Bh, acc2[mt2], 0, 0, 0);
                acc2[mt2] = __builtin_amdgcn_mfma_f32_16x16x32_bf16(ah, Bl, acc2[mt2], 0, 0, 0);
                acc2[mt2] = __builtin_amdgcn_mfma_f32_16x16x32_bf16(ah, Bh, acc2[mt2], 0, 0, 0);
            }
        }

        // layer 3: prelu + dot W3, reduce over lane-groups, write scores
        float part = 0.f;
        #pragma unroll
        for (int mt2 = 0; mt2 < 2; ++mt2) {
            #pragma unroll
            for (int i = 0; i < 4; ++i) {
                float v = acc2[mt2][i] + b2v[mt2][i];
                v = v > 0.f ? v : a2v * v;
                part += v * w3v[mt2][i];
            }
        }
        part += __shfl_xor(part, 16);
        part += __shfl_xor(part, 32);
        if (lane < 16 && s < 200)
            scores[((size_t)b * H + h) * S + s] = part + b3v;
    }
}

// ---------------------------------------------------------------------------
// Attend kernel (proven in round 1): per b — masked softmax per head,
// weighted key sum, head mean, fused output projection.
// ---------------------------------------------------------------------------
__global__ __launch_bounds__(256) void attend_kernel(
    const float* __restrict__ keys, const int* __restrict__ mask,
    const float* __restrict__ scores, const float* __restrict__ Wo,
    const float* __restrict__ bo, float* __restrict__ out)
{
    __shared__ float4 sw4[S];
    __shared__ float  sred[4 * H * D];
    __shared__ float  scomb[D];

    const int b = blockIdx.x;
    const int t = threadIdx.x;
    const int wave = t >> 6;
    const int lane = t & 63;

    {
        const int hh = wave;
        const float* srow = scores + ((size_t)b * H + hh) * S;
        float v[4]; int valid[4];
        float M = -INFINITY;
        #pragma unroll
        for (int c = 0; c < 4; ++c) {
            const int s = lane + 64 * c;
            const bool ok = (s < S);
            valid[c] = ok ? mask[(size_t)b * S + s] : 0;
            v[c] = (ok && valid[c]) ? srow[s] : -INFINITY;
            M = fmaxf(M, v[c]);
        }
        #pragma unroll
        for (int off = 32; off > 0; off >>= 1) M = fmaxf(M, __shfl_xor(M, off));
        float e[4]; float Z = 0.f;
        #pragma unroll
        for (int c = 0; c < 4; ++c) { e[c] = valid[c] ? __expf(v[c] - M) : 0.f; Z += e[c]; }
        #pragma unroll
        for (int off = 32; off > 0; off >>= 1) Z += __shfl_xor(Z, off);
        const float inv = (Z > 0.f) ? 1.f / Z : 0.f;
        #pragma unroll
        for (int c = 0; c < 4; ++c) {
            const int s = lane + 64 * c;
            if (s < S) reinterpret_cast<float*>(&sw4[s])[hh] = e[c] * inv;
        }
    }
    __syncthreads();

    {
        const int d = t & 63, sg = t >> 6;
        float a0 = 0.f, a1 = 0.f, a2 = 0.f, a3 = 0.f;
        #pragma unroll 2
        for (int i = 0; i < 50; ++i) {
            const int s = sg * 50 + i;
            const float kv = keys[((size_t)b * S + s) * D + d];
            const float4 wv = sw4[s];
            a0 += wv.x * kv; a1 += wv.y * kv; a2 += wv.z * kv; a3 += wv.w * kv;
        }
        sred[(sg * H + 0) * D + d] = a0; sred[(sg * H + 1) * D + d] = a1;
        sred[(sg * H + 2) * D + d] = a2; sred[(sg * H + 3) * D + d] = a3;
    }
    __syncthreads();
    if (t < D) {
        float c = 0.f;
        #pragma unroll
        for (int i = 0; i < 4 * H; ++i) c += sred[i * D + t];
        scomb[t] = c * (1.0f / H);
    }
    __syncthreads();
    {
        __shared__ float po[4][D];
        const int col = t & 63, gq = t >> 6;
        float p = 0.f;
        #pragma unroll
        for (int j = 0; j < 16; ++j) { int dd = gq * 16 + j; p += scomb[dd] * Wo[dd * 64 + col]; }
        po[gq][col] = p;
        __syncthreads();
        if (t < D) {
            float o = bo[t];
            #pragma unroll
            for (int q = 0; q < 4; ++q) o += po[q][t];
            out[(size_t)b * D + t] = o;
        }
    }
}

// ---------------------------------------------------------------------------
extern "C" void kernel_launch(void* const* d_in, const int* in_sizes, int n_in,
                              void* d_out, int out_size, void* d_ws, size_t ws_size,
                              hipStream_t stream) {
    const float* query = (const float*)d_in[0];
    const float* keys  = (const float*)d_in[1];
    const int*   mask  = (const int*)d_in[2];
    const float* W1 = (const float*)d_in[3];
    const float* b1 = (const float*)d_in[4];
    const float* a1 = (const float*)d_in[5];
    const float* W2 = (const float*)d_in[6];
    const float* b2 = (const float*)d_in[7];
    const float* a2 = (const float*)d_in[8];
    const float* W3 = (const float*)d_in[9];
    const float* b3 = (const float*)d_in[10];
    const float* Wo = (const float*)d_in[11];
    const float* bo = (const float*)d_in[12];

    float* out    = (float*)d_out;
    float* scores = (float*)d_ws;   // B*H*S floats = 6.55 MB

    score_kernel<<<dim3(B * H), 256, 0, stream>>>(query, keys, W1, b1, a1,
                                                  W2, b2, a2, W3, b3, scores);
    attend_kernel<<<dim3(B), 256, 0, stream>>>(keys, mask, scores, Wo, bo, out);
}